// Round 2
// baseline (2250.749 us; speedup 1.0000x reference)
//
#include <hip/hip_runtime.h>

#define N_NODES 100000
#define N_EDGES 600000
#define DIM 128

typedef __attribute__((ext_vector_type(8))) short short8;   // 8 bf16 (4 VGPRs) — MFMA A/B frag
typedef __attribute__((ext_vector_type(4))) float floatx4;  // MFMA C/D frag
typedef unsigned short ushort_t;

#define MFMA(a, b, c) __builtin_amdgcn_mfma_f32_16x16x32_bf16((a), (b), (c), 0, 0, 0)

__device__ __forceinline__ unsigned short f2bf(float f) {
    unsigned int u = __float_as_uint(f);
    u += 0x7fffu + ((u >> 16) & 1u);   // round-to-nearest-even
    return (unsigned short)(u >> 16);
}

__device__ __forceinline__ short8 pack8(const float4& a, const float4& b) {
    short8 r;
    r[0] = (short)f2bf(a.x); r[1] = (short)f2bf(a.y);
    r[2] = (short)f2bf(a.z); r[3] = (short)f2bf(a.w);
    r[4] = (short)f2bf(b.x); r[5] = (short)f2bf(b.y);
    r[6] = (short)f2bf(b.z); r[7] = (short)f2bf(b.w);
    return r;
}

__device__ __forceinline__ float mish_f(float v) {
    // mish(x) = x * tanh(softplus(x)); tanh(ln(z)) = (z^2-1)/(z^2+1), z = 1+e^x
    if (v > 30.0f) return v;
    float t = __expf(v);
    float z = 1.0f + t;
    float z2 = z * z;
    return v * (z2 - 1.0f) / (z2 + 1.0f);
}

// Load one B-fragment of W (row-major [K][128] fp32) for col-tile ct, k-tile kt.
// Lane l needs W[kt*32 + (l>>4)*8 + j][ct*16 + (l&15)], j=0..7.  Quarter-wave
// reads are 64B-contiguous; W is L2-hot after the first block touches it.
__device__ __forceinline__ short8 load_bfrag(const float* __restrict__ W,
                                             int ct, int kt, int lane) {
    const float* p = W + (size_t)(kt * 32 + (lane >> 4) * 8) * DIM + ct * 16 + (lane & 15);
    short8 r;
    #pragma unroll
    for (int j = 0; j < 8; ++j) r[j] = (short)f2bf(p[(size_t)j * DIM]);
    return r;
}

// Shared 2-layer MLP on a 32-row tile: [32,256]@[256,128] -> mish -> [32,128]@[128,128].
// 4 waves; wave w owns output cols [32w, 32w+32).  s_in/s_h are XOR-granule-swizzled
// (granule = 16B; g' = g ^ (row&7)) so the strided A-frag ds_read_b128s are ~2-way.
__device__ __forceinline__ void mlp_tile_mfma(
    const ushort_t* __restrict__ s_in, ushort_t* __restrict__ s_h,
    const short8 (&w1f)[2][8], const short8 (&w2f)[2][4],
    const float (&b1v)[2], const float (&b2v)[2],
    float* __restrict__ out_row0, int wave, int lane)
{
    const int r0 = lane & 15;
    const int r1 = 16 + r0;
    const int sw = r0 & 7;          // swizzle key (same for r0 and r1)
    const int q  = lane >> 4;       // quarter-wave id

    floatx4 acc00 = {0.f,0.f,0.f,0.f}, acc01 = acc00, acc10 = acc00, acc11 = acc00;
    #pragma unroll
    for (int kt = 0; kt < 8; ++kt) {
        const int g = kt * 4 + q;
        short8 a0 = *(const short8*)&s_in[r0 * 256 + (g ^ sw) * 8];
        short8 a1 = *(const short8*)&s_in[r1 * 256 + (g ^ sw) * 8];
        acc00 = MFMA(a0, w1f[0][kt], acc00);
        acc01 = MFMA(a0, w1f[1][kt], acc01);
        acc10 = MFMA(a1, w1f[0][kt], acc10);
        acc11 = MFMA(a1, w1f[1][kt], acc11);
    }

    // bias + mish -> bf16 -> swizzled s_h.  D layout: col = lane&15, row = q*4 + i.
    #pragma unroll
    for (int rt = 0; rt < 2; ++rt) {
        #pragma unroll
        for (int ct = 0; ct < 2; ++ct) {
            const floatx4 v = rt == 0 ? (ct == 0 ? acc00 : acc01)
                                      : (ct == 0 ? acc10 : acc11);
            const int col = (2 * wave + ct) * 16 + (lane & 15);
            const int gq = col >> 3, bq = col & 7;
            #pragma unroll
            for (int i = 0; i < 4; ++i) {
                const int row = rt * 16 + q * 4 + i;
                s_h[row * 128 + (gq ^ (row & 7)) * 8 + bq] = f2bf(mish_f(v[i] + b1v[ct]));
            }
        }
    }
    __syncthreads();

    floatx4 bcc00 = {0.f,0.f,0.f,0.f}, bcc01 = bcc00, bcc10 = bcc00, bcc11 = bcc00;
    #pragma unroll
    for (int kt = 0; kt < 4; ++kt) {
        const int g = kt * 4 + q;
        short8 a0 = *(const short8*)&s_h[r0 * 128 + (g ^ sw) * 8];
        short8 a1 = *(const short8*)&s_h[r1 * 128 + (g ^ sw) * 8];
        bcc00 = MFMA(a0, w2f[0][kt], bcc00);
        bcc01 = MFMA(a0, w2f[1][kt], bcc01);
        bcc10 = MFMA(a1, w2f[0][kt], bcc10);
        bcc11 = MFMA(a1, w2f[1][kt], bcc11);
    }

    // fp32 out; each quarter-wave's 16 lanes write 64B contiguous.
    #pragma unroll
    for (int rt = 0; rt < 2; ++rt) {
        #pragma unroll
        for (int ct = 0; ct < 2; ++ct) {
            const floatx4 v = rt == 0 ? (ct == 0 ? bcc00 : bcc01)
                                      : (ct == 0 ? bcc10 : bcc11);
            const int col = (2 * wave + ct) * 16 + (lane & 15);
            #pragma unroll
            for (int i = 0; i < 4; ++i) {
                const int row = rt * 16 + q * 4 + i;
                out_row0[(size_t)row * DIM + col] = v[i] + b2v[ct];
            }
        }
    }
}

__global__ __launch_bounds__(256)
void edge_kernel(const float* __restrict__ x, const float* __restrict__ edge_attr,
                 const int* __restrict__ src_idx, const int* __restrict__ dst_idx,
                 const float* __restrict__ W1, const float* __restrict__ b1,
                 const float* __restrict__ W2, const float* __restrict__ b2,
                 float* __restrict__ e_out, float* __restrict__ agg)
{
    __shared__ ushort_t s_in[32 * 256];
    __shared__ ushort_t s_h[32 * 128];
    const int tid = threadIdx.x;
    const int wave = tid >> 6, lane = tid & 63;

    // per-wave weight fragments, resident in VGPRs for the whole grid-stride loop
    short8 w1f[2][8], w2f[2][4];
    float b1v[2], b2v[2];
    #pragma unroll
    for (int ct = 0; ct < 2; ++ct) {
        const int c = (2 * wave + ct) * 16 + (lane & 15);
        b1v[ct] = b1[c];
        b2v[ct] = b2[c];
        #pragma unroll
        for (int kt = 0; kt < 8; ++kt) w1f[ct][kt] = load_bfrag(W1, 2 * wave + ct, kt, lane);
        #pragma unroll
        for (int kt = 0; kt < 4; ++kt) w2f[ct][kt] = load_bfrag(W2, 2 * wave + ct, kt, lane);
    }

    const int ntiles = N_EDGES / 32;
    for (int t = blockIdx.x; t < ntiles; t += gridDim.x) {
        const int e_base = t * 32;
        // stage cols 0..127 = edge_attr (bf16) + fused fp32 atomic scatter into agg
        #pragma unroll
        for (int p = 0; p < 2; ++p) {
            const int gi = tid + p * 256;
            const int r = gi >> 4, gq = gi & 15;
            const float* pe = edge_attr + (size_t)(e_base + r) * DIM + gq * 8;
            const float4 v0 = *(const float4*)pe;
            const float4 v1 = *(const float4*)(pe + 4);
            *(short8*)&s_in[r * 256 + (gq ^ (r & 7)) * 8] = pack8(v0, v1);
            const int d = dst_idx[e_base + r];
            float* ap = agg + (size_t)d * DIM + gq * 8;
            atomicAdd(ap + 0, v0.x); atomicAdd(ap + 1, v0.y);
            atomicAdd(ap + 2, v0.z); atomicAdd(ap + 3, v0.w);
            atomicAdd(ap + 4, v1.x); atomicAdd(ap + 5, v1.y);
            atomicAdd(ap + 6, v1.z); atomicAdd(ap + 7, v1.w);
        }
        // stage cols 128..255 = x[src] + x[dst]
        #pragma unroll
        for (int p = 0; p < 2; ++p) {
            const int gi = tid + p * 256;
            const int r = gi >> 4, gq = gi & 15;
            const int s = src_idx[e_base + r];
            const int d = dst_idx[e_base + r];
            const float* ps = x + (size_t)s * DIM + gq * 8;
            const float* pd = x + (size_t)d * DIM + gq * 8;
            const float4 s0 = *(const float4*)ps, s1 = *(const float4*)(ps + 4);
            const float4 d0 = *(const float4*)pd, d1 = *(const float4*)(pd + 4);
            float4 u0, u1;
            u0.x = s0.x + d0.x; u0.y = s0.y + d0.y; u0.z = s0.z + d0.z; u0.w = s0.w + d0.w;
            u1.x = s1.x + d1.x; u1.y = s1.y + d1.y; u1.z = s1.z + d1.z; u1.w = s1.w + d1.w;
            *(short8*)&s_in[r * 256 + ((16 + gq) ^ (r & 7)) * 8] = pack8(u0, u1);
        }
        __syncthreads();   // staging done; also fences prior iter's s_h readers
        mlp_tile_mfma(s_in, s_h, w1f, w2f, b1v, b2v,
                      e_out + (size_t)e_base * DIM, wave, lane);
    }
}

__global__ __launch_bounds__(256)
void node_kernel(const float* __restrict__ x, const float* __restrict__ agg,
                 const float* __restrict__ W1, const float* __restrict__ b1,
                 const float* __restrict__ W2, const float* __restrict__ b2,
                 float* __restrict__ x_out)
{
    __shared__ ushort_t s_in[32 * 256];
    __shared__ ushort_t s_h[32 * 128];
    const int tid = threadIdx.x;
    const int wave = tid >> 6, lane = tid & 63;

    short8 w1f[2][8], w2f[2][4];
    float b1v[2], b2v[2];
    #pragma unroll
    for (int ct = 0; ct < 2; ++ct) {
        const int c = (2 * wave + ct) * 16 + (lane & 15);
        b1v[ct] = b1[c];
        b2v[ct] = b2[c];
        #pragma unroll
        for (int kt = 0; kt < 8; ++kt) w1f[ct][kt] = load_bfrag(W1, 2 * wave + ct, kt, lane);
        #pragma unroll
        for (int kt = 0; kt < 4; ++kt) w2f[ct][kt] = load_bfrag(W2, 2 * wave + ct, kt, lane);
    }

    const int ntiles = N_NODES / 32;
    for (int t = blockIdx.x; t < ntiles; t += gridDim.x) {
        const int n_base = t * 32;
        #pragma unroll
        for (int p = 0; p < 2; ++p) {
            const int gi = tid + p * 256;
            const int r = gi >> 4, gq = gi & 15;
            const float* px = x   + (size_t)(n_base + r) * DIM + gq * 8;
            const float* pa = agg + (size_t)(n_base + r) * DIM + gq * 8;
            *(short8*)&s_in[r * 256 + (gq ^ (r & 7)) * 8] =
                pack8(*(const float4*)px, *(const float4*)(px + 4));
            *(short8*)&s_in[r * 256 + ((16 + gq) ^ (r & 7)) * 8] =
                pack8(*(const float4*)pa, *(const float4*)(pa + 4));
        }
        __syncthreads();
        mlp_tile_mfma(s_in, s_h, w1f, w2f, b1v, b2v,
                      x_out + (size_t)n_base * DIM, wave, lane);
    }
}

extern "C" void kernel_launch(void* const* d_in, const int* in_sizes, int n_in,
                              void* d_out, int out_size, void* d_ws, size_t ws_size,
                              hipStream_t stream)
{
    const float* x         = (const float*)d_in[0];
    const float* edge_attr = (const float*)d_in[1];
    const int*   ei        = (const int*)d_in[2];   // [2, E]: src row then dst row
    const float* eW1 = (const float*)d_in[3];
    const float* eb1 = (const float*)d_in[4];
    const float* eW2 = (const float*)d_in[5];
    const float* eb2 = (const float*)d_in[6];
    const float* nW1 = (const float*)d_in[7];
    const float* nb1 = (const float*)d_in[8];
    const float* nW2 = (const float*)d_in[9];
    const float* nb2 = (const float*)d_in[10];

    float* out   = (float*)d_out;
    float* x_out = out;                             // [N, 128]
    float* e_out = out + (size_t)N_NODES * DIM;     // [E, 128]
    float* agg   = (float*)d_ws;                    // [N, 128] fp32 scratch

    const int* src_idx = ei;
    const int* dst_idx = ei + N_EDGES;

    hipMemsetAsync(agg, 0, (size_t)N_NODES * DIM * sizeof(float), stream);

    edge_kernel<<<dim3(4096), dim3(256), 0, stream>>>(
        x, edge_attr, src_idx, dst_idx, eW1, eb1, eW2, eb2, e_out, agg);

    node_kernel<<<dim3(2048), dim3(256), 0, stream>>>(
        x, agg, nW1, nb1, nW2, nb2, x_out);
}

// Round 3
// 642.076 us; speedup vs baseline: 3.5054x; 3.5054x over previous
//
#include <hip/hip_runtime.h>

#define N_NODES 100000
#define N_EDGES 600000
#define DIM 128

typedef __attribute__((ext_vector_type(8))) short short8;   // 8 bf16 (4 VGPRs) — MFMA A/B frag
typedef __attribute__((ext_vector_type(4))) float floatx4;  // MFMA C/D frag
typedef unsigned short ushort_t;

#define MFMA(a, b, c) __builtin_amdgcn_mfma_f32_16x16x32_bf16((a), (b), (c), 0, 0, 0)

__device__ __forceinline__ unsigned short f2bf(float f) {
    unsigned int u = __float_as_uint(f);
    u += 0x7fffu + ((u >> 16) & 1u);   // round-to-nearest-even
    return (unsigned short)(u >> 16);
}

__device__ __forceinline__ short8 pack8(const float4& a, const float4& b) {
    short8 r;
    r[0] = (short)f2bf(a.x); r[1] = (short)f2bf(a.y);
    r[2] = (short)f2bf(a.z); r[3] = (short)f2bf(a.w);
    r[4] = (short)f2bf(b.x); r[5] = (short)f2bf(b.y);
    r[6] = (short)f2bf(b.z); r[7] = (short)f2bf(b.w);
    return r;
}

__device__ __forceinline__ float mish_f(float v) {
    if (v > 30.0f) return v;
    float t = __expf(v);
    float z = 1.0f + t;
    float z2 = z * z;
    return v * (z2 - 1.0f) / (z2 + 1.0f);
}

// B-fragment of W (row-major [K][128] fp32) for col-tile ct, k-tile kt.
__device__ __forceinline__ short8 load_bfrag(const float* __restrict__ W,
                                             int ct, int kt, int lane) {
    const float* p = W + (size_t)(kt * 32 + (lane >> 4) * 8) * DIM + ct * 16 + (lane & 15);
    short8 r;
    #pragma unroll
    for (int j = 0; j < 8; ++j) r[j] = (short)f2bf(p[(size_t)j * DIM]);
    return r;
}

// Shared 2-layer MLP on a 32-row LDS tile (XOR-granule swizzle, granule=16B, g^=row&7).
__device__ __forceinline__ void mlp_tile_mfma(
    const ushort_t* __restrict__ s_in, ushort_t* __restrict__ s_h,
    const short8 (&w1f)[2][8], const short8 (&w2f)[2][4],
    const float (&b1v)[2], const float (&b2v)[2],
    float* __restrict__ out_row0, int wave, int lane)
{
    const int r0 = lane & 15;
    const int r1 = 16 + r0;
    const int sw = r0 & 7;
    const int q  = lane >> 4;

    floatx4 acc00 = {0.f,0.f,0.f,0.f}, acc01 = acc00, acc10 = acc00, acc11 = acc00;
    #pragma unroll
    for (int kt = 0; kt < 8; ++kt) {
        const int g = kt * 4 + q;
        short8 a0 = *(const short8*)&s_in[r0 * 256 + (g ^ sw) * 8];
        short8 a1 = *(const short8*)&s_in[r1 * 256 + (g ^ sw) * 8];
        acc00 = MFMA(a0, w1f[0][kt], acc00);
        acc01 = MFMA(a0, w1f[1][kt], acc01);
        acc10 = MFMA(a1, w1f[0][kt], acc10);
        acc11 = MFMA(a1, w1f[1][kt], acc11);
    }

    #pragma unroll
    for (int rt = 0; rt < 2; ++rt) {
        #pragma unroll
        for (int ct = 0; ct < 2; ++ct) {
            const floatx4 v = rt == 0 ? (ct == 0 ? acc00 : acc01)
                                      : (ct == 0 ? acc10 : acc11);
            const int col = (2 * wave + ct) * 16 + (lane & 15);
            const int gq = col >> 3, bq = col & 7;
            #pragma unroll
            for (int i = 0; i < 4; ++i) {
                const int row = rt * 16 + q * 4 + i;
                s_h[row * 128 + (gq ^ (row & 7)) * 8 + bq] = f2bf(mish_f(v[i] + b1v[ct]));
            }
        }
    }
    __syncthreads();

    floatx4 bcc00 = {0.f,0.f,0.f,0.f}, bcc01 = bcc00, bcc10 = bcc00, bcc11 = bcc00;
    #pragma unroll
    for (int kt = 0; kt < 4; ++kt) {
        const int g = kt * 4 + q;
        short8 a0 = *(const short8*)&s_h[r0 * 128 + (g ^ sw) * 8];
        short8 a1 = *(const short8*)&s_h[r1 * 128 + (g ^ sw) * 8];
        bcc00 = MFMA(a0, w2f[0][kt], bcc00);
        bcc01 = MFMA(a0, w2f[1][kt], bcc01);
        bcc10 = MFMA(a1, w2f[0][kt], bcc10);
        bcc11 = MFMA(a1, w2f[1][kt], bcc11);
    }

    #pragma unroll
    for (int rt = 0; rt < 2; ++rt) {
        #pragma unroll
        for (int ct = 0; ct < 2; ++ct) {
            const floatx4 v = rt == 0 ? (ct == 0 ? bcc00 : bcc01)
                                      : (ct == 0 ? bcc10 : bcc11);
            const int col = (2 * wave + ct) * 16 + (lane & 15);
            #pragma unroll
            for (int i = 0; i < 4; ++i) {
                const int row = rt * 16 + q * 4 + i;
                out_row0[(size_t)row * DIM + col] = v[i] + b2v[ct];
            }
        }
    }
}

// ---------- CSR construction (replaces 76.8M fp32 atomics with 1.2M int atomics) ----------

__global__ __launch_bounds__(256)
void hist_kernel(const int* __restrict__ dst_idx, int* __restrict__ deg) {
    const int e = blockIdx.x * 256 + threadIdx.x;
    if (e < N_EDGES) atomicAdd(&deg[dst_idx[e]], 1);
}

__global__ __launch_bounds__(1024)
void scan_kernel(const int* __restrict__ deg, int* __restrict__ rowptr,
                 int* __restrict__ cursor) {
    __shared__ int part[1024];
    const int t = threadIdx.x;
    const int CH = 98;                       // 1024*98 = 100352 >= N_NODES
    const int b = t * CH;
    const int e = min(b + CH, N_NODES);
    int s = 0;
    for (int i = b; i < e; ++i) s += deg[i];
    part[t] = s;
    __syncthreads();
    for (int d = 1; d < 1024; d <<= 1) {     // Hillis-Steele inclusive scan
        int v = (t >= d) ? part[t - d] : 0;
        __syncthreads();
        part[t] += v;
        __syncthreads();
    }
    int run = part[t] - s;                   // exclusive offset
    for (int i = b; i < e; ++i) {
        rowptr[i] = run;
        cursor[i] = run;
        run += deg[i];
    }
    if (t == 1023) rowptr[N_NODES] = run;    // == N_EDGES
}

__global__ __launch_bounds__(256)
void scatter_kernel(const int* __restrict__ dst_idx, int* __restrict__ cursor,
                    int* __restrict__ perm) {
    const int e = blockIdx.x * 256 + threadIdx.x;
    if (e < N_EDGES) {
        const int pos = atomicAdd(&cursor[dst_idx[e]], 1);
        perm[pos] = e;
    }
}

// ---------- main kernels ----------

__global__ __launch_bounds__(256)
void edge_kernel(const float* __restrict__ x, const float* __restrict__ edge_attr,
                 const int* __restrict__ src_idx, const int* __restrict__ dst_idx,
                 const float* __restrict__ W1, const float* __restrict__ b1,
                 const float* __restrict__ W2, const float* __restrict__ b2,
                 float* __restrict__ e_out)
{
    __shared__ ushort_t s_in[32 * 256];
    __shared__ ushort_t s_h[32 * 128];
    const int tid = threadIdx.x;
    const int wave = tid >> 6, lane = tid & 63;

    short8 w1f[2][8], w2f[2][4];
    float b1v[2], b2v[2];
    #pragma unroll
    for (int ct = 0; ct < 2; ++ct) {
        const int c = (2 * wave + ct) * 16 + (lane & 15);
        b1v[ct] = b1[c];
        b2v[ct] = b2[c];
        #pragma unroll
        for (int kt = 0; kt < 8; ++kt) w1f[ct][kt] = load_bfrag(W1, 2 * wave + ct, kt, lane);
        #pragma unroll
        for (int kt = 0; kt < 4; ++kt) w2f[ct][kt] = load_bfrag(W2, 2 * wave + ct, kt, lane);
    }

    const int ntiles = N_EDGES / 32;
    for (int t = blockIdx.x; t < ntiles; t += gridDim.x) {
        const int e_base = t * 32;
        #pragma unroll
        for (int p = 0; p < 2; ++p) {
            const int gi = tid + p * 256;
            const int r = gi >> 4, gq = gi & 15;
            const float* pe = edge_attr + (size_t)(e_base + r) * DIM + gq * 8;
            const float4 v0 = *(const float4*)pe;
            const float4 v1 = *(const float4*)(pe + 4);
            *(short8*)&s_in[r * 256 + (gq ^ (r & 7)) * 8] = pack8(v0, v1);
        }
        #pragma unroll
        for (int p = 0; p < 2; ++p) {
            const int gi = tid + p * 256;
            const int r = gi >> 4, gq = gi & 15;
            const int s = src_idx[e_base + r];
            const int d = dst_idx[e_base + r];
            const float* ps = x + (size_t)s * DIM + gq * 8;
            const float* pd = x + (size_t)d * DIM + gq * 8;
            const float4 s0 = *(const float4*)ps, s1 = *(const float4*)(ps + 4);
            const float4 d0 = *(const float4*)pd, d1 = *(const float4*)(pd + 4);
            float4 u0, u1;
            u0.x = s0.x + d0.x; u0.y = s0.y + d0.y; u0.z = s0.z + d0.z; u0.w = s0.w + d0.w;
            u1.x = s1.x + d1.x; u1.y = s1.y + d1.y; u1.z = s1.z + d1.z; u1.w = s1.w + d1.w;
            *(short8*)&s_in[r * 256 + ((16 + gq) ^ (r & 7)) * 8] = pack8(u0, u1);
        }
        __syncthreads();
        mlp_tile_mfma(s_in, s_h, w1f, w2f, b1v, b2v,
                      e_out + (size_t)e_base * DIM, wave, lane);
    }
}

__global__ __launch_bounds__(256)
void node_kernel(const float* __restrict__ x, const float* __restrict__ edge_attr,
                 const int* __restrict__ rowptr, const int* __restrict__ perm,
                 const float* __restrict__ W1, const float* __restrict__ b1,
                 const float* __restrict__ W2, const float* __restrict__ b2,
                 float* __restrict__ x_out)
{
    __shared__ ushort_t s_in[32 * 256];
    __shared__ ushort_t s_h[32 * 128];
    const int tid = threadIdx.x;
    const int wave = tid >> 6, lane = tid & 63;

    short8 w1f[2][8], w2f[2][4];
    float b1v[2], b2v[2];
    #pragma unroll
    for (int ct = 0; ct < 2; ++ct) {
        const int c = (2 * wave + ct) * 16 + (lane & 15);
        b1v[ct] = b1[c];
        b2v[ct] = b2[c];
        #pragma unroll
        for (int kt = 0; kt < 8; ++kt) w1f[ct][kt] = load_bfrag(W1, 2 * wave + ct, kt, lane);
        #pragma unroll
        for (int kt = 0; kt < 4; ++kt) w2f[ct][kt] = load_bfrag(W2, 2 * wave + ct, kt, lane);
    }

    const int ntiles = N_NODES / 32;     // 3125 exact
    for (int t = blockIdx.x; t < ntiles; t += gridDim.x) {
        const int n_base = t * 32;
        const int r = tid >> 3;          // node row 0..31
        const int c = tid & 7;           // 16-col group 0..7
        const int n = n_base + r;
        const int swr = r & 7;

        const float* px = x + (size_t)n * DIM + c * 16;
        const float4 xv0 = *(const float4*)(px + 0);
        const float4 xv1 = *(const float4*)(px + 4);
        const float4 xv2 = *(const float4*)(px + 8);
        const float4 xv3 = *(const float4*)(px + 12);

        // gather-sum this node's incoming edge_attr rows (CSR): fp32, register acc
        float4 a0 = {0,0,0,0}, a1 = a0, a2 = a0, a3 = a0;
        const int k0 = rowptr[n], k1 = rowptr[n + 1];
        for (int k = k0; k < k1; ++k) {
            const int e = perm[k];
            const float* pe = edge_attr + (size_t)e * DIM + c * 16;
            const float4 v0 = *(const float4*)(pe + 0);
            const float4 v1 = *(const float4*)(pe + 4);
            const float4 v2 = *(const float4*)(pe + 8);
            const float4 v3 = *(const float4*)(pe + 12);
            a0.x += v0.x; a0.y += v0.y; a0.z += v0.z; a0.w += v0.w;
            a1.x += v1.x; a1.y += v1.y; a1.z += v1.z; a1.w += v1.w;
            a2.x += v2.x; a2.y += v2.y; a2.z += v2.z; a2.w += v2.w;
            a3.x += v3.x; a3.y += v3.y; a3.z += v3.z; a3.w += v3.w;
        }

        *(short8*)&s_in[r * 256 + ((2 * c)     ^ swr) * 8] = pack8(xv0, xv1);
        *(short8*)&s_in[r * 256 + ((2 * c + 1) ^ swr) * 8] = pack8(xv2, xv3);
        *(short8*)&s_in[r * 256 + ((16 + 2 * c)     ^ swr) * 8] = pack8(a0, a1);
        *(short8*)&s_in[r * 256 + ((16 + 2 * c + 1) ^ swr) * 8] = pack8(a2, a3);
        __syncthreads();
        mlp_tile_mfma(s_in, s_h, w1f, w2f, b1v, b2v,
                      x_out + (size_t)n_base * DIM, wave, lane);
    }
}

extern "C" void kernel_launch(void* const* d_in, const int* in_sizes, int n_in,
                              void* d_out, int out_size, void* d_ws, size_t ws_size,
                              hipStream_t stream)
{
    const float* x         = (const float*)d_in[0];
    const float* edge_attr = (const float*)d_in[1];
    const int*   ei        = (const int*)d_in[2];   // [2, E]: src row then dst row
    const float* eW1 = (const float*)d_in[3];
    const float* eb1 = (const float*)d_in[4];
    const float* eW2 = (const float*)d_in[5];
    const float* eb2 = (const float*)d_in[6];
    const float* nW1 = (const float*)d_in[7];
    const float* nb1 = (const float*)d_in[8];
    const float* nW2 = (const float*)d_in[9];
    const float* nb2 = (const float*)d_in[10];

    float* out   = (float*)d_out;
    float* x_out = out;                             // [N, 128]
    float* e_out = out + (size_t)N_NODES * DIM;     // [E, 128]

    const int* src_idx = ei;
    const int* dst_idx = ei + N_EDGES;

    // workspace: deg | rowptr | cursor | perm  (ints, 128-aligned chunks)
    int* wsi    = (int*)d_ws;
    int* deg    = wsi;                    // N
    int* rowptr = wsi + 100352;           // N+1
    int* cursor = wsi + 2 * 100352;       // N
    int* perm   = wsi + 3 * 100352;       // E

    hipMemsetAsync(deg, 0, (size_t)N_NODES * sizeof(int), stream);

    const int egrid = (N_EDGES + 255) / 256;
    hist_kernel   <<<dim3(egrid), dim3(256),  0, stream>>>(dst_idx, deg);
    scan_kernel   <<<dim3(1),     dim3(1024), 0, stream>>>(deg, rowptr, cursor);
    scatter_kernel<<<dim3(egrid), dim3(256),  0, stream>>>(dst_idx, cursor, perm);

    edge_kernel<<<dim3(4096), dim3(256), 0, stream>>>(
        x, edge_attr, src_idx, dst_idx, eW1, eb1, eW2, eb2, e_out);

    node_kernel<<<dim3(2048), dim3(256), 0, stream>>>(
        x, edge_attr, rowptr, perm, nW1, nb1, nW2, nb2, x_out);
}

// Round 4
// 411.118 us; speedup vs baseline: 5.4747x; 1.5618x over previous
//
#include <hip/hip_runtime.h>

#define N_NODES 100000
#define N_EDGES 600000
#define DIM 128

typedef __attribute__((ext_vector_type(8))) short short8;   // 8 bf16 (4 VGPRs)
typedef __attribute__((ext_vector_type(4))) float floatx4;  // MFMA C/D frag
typedef unsigned short ushort_t;

#define MFMA(a,b,c) __builtin_amdgcn_mfma_f32_16x16x32_bf16((a),(b),(c),0,0,0)

__device__ __forceinline__ unsigned short f2bf(float f) {
    unsigned int u = __float_as_uint(f);
    u += 0x7fffu + ((u >> 16) & 1u);   // round-to-nearest-even
    return (unsigned short)(u >> 16);
}

__device__ __forceinline__ short8 pack8(const float4& a, const float4& b) {
    short8 r;
    r[0] = (short)f2bf(a.x); r[1] = (short)f2bf(a.y);
    r[2] = (short)f2bf(a.z); r[3] = (short)f2bf(a.w);
    r[4] = (short)f2bf(b.x); r[5] = (short)f2bf(b.y);
    r[6] = (short)f2bf(b.z); r[7] = (short)f2bf(b.w);
    return r;
}

__device__ __forceinline__ float mish_f(float v) {
    if (v > 30.0f) return v;
    float t = __expf(v);
    float z = 1.0f + t;
    float z2 = z * z;
    return v * (z2 - 1.0f) / (z2 + 1.0f);
}

// B-fragment of W (row-major [K][128] fp32) for col-tile ct, k-tile kt.
__device__ __forceinline__ short8 load_bfrag(const float* __restrict__ W,
                                             int ct, int kt, int lane) {
    const float* p = W + (size_t)(kt * 32 + (lane >> 4) * 8) * DIM + ct * 16 + (lane & 15);
    short8 r;
    #pragma unroll
    for (int j = 0; j < 8; ++j) r[j] = (short)f2bf(p[(size_t)j * DIM]);
    return r;
}

// MLP compute on a staged 32-row tile. 8 waves; wave w owns cols [16w,16w+16).
// s_in/s_h: XOR-granule swizzle (granule=16B, phys = g ^ (row&7)).
__device__ __forceinline__ void mlp_core(
    const ushort_t* __restrict__ s_in, ushort_t* __restrict__ s_h,
    const short8 (&w1f)[8], const short8 (&w2f)[4],
    float b1v, float b2v, float* __restrict__ out, int wave, int lane)
{
    const int r0 = lane & 15, q = lane >> 4, sw = lane & 7;

    floatx4 acc0 = {0.f,0.f,0.f,0.f}, acc1 = acc0;
    #pragma unroll
    for (int kt = 0; kt < 8; ++kt) {
        const int g = kt * 4 + q;
        short8 a0 = *(const short8*)&s_in[r0 * 256 + (g ^ sw) * 8];
        short8 a1 = *(const short8*)&s_in[(16 + r0) * 256 + (g ^ sw) * 8];
        acc0 = MFMA(a0, w1f[kt], acc0);
        acc1 = MFMA(a1, w1f[kt], acc1);
    }

    const int colg = wave * 2 + (r0 >> 3);   // 8-col granule index of our column
    const int bq   = r0 & 7;
    #pragma unroll
    for (int i = 0; i < 4; ++i) {
        int row = q * 4 + i;
        s_h[row * 128 + (colg ^ (row & 7)) * 8 + bq] = f2bf(mish_f(acc0[i] + b1v));
        row += 16;
        s_h[row * 128 + (colg ^ (row & 7)) * 8 + bq] = f2bf(mish_f(acc1[i] + b1v));
    }
    __syncthreads();   // B2: s_h visible

    floatx4 c0 = {0.f,0.f,0.f,0.f}, c1 = c0;
    #pragma unroll
    for (int kt = 0; kt < 4; ++kt) {
        const int g = kt * 4 + q;
        short8 a0 = *(const short8*)&s_h[r0 * 128 + (g ^ sw) * 8];
        short8 a1 = *(const short8*)&s_h[(16 + r0) * 128 + (g ^ sw) * 8];
        c0 = MFMA(a0, w2f[kt], c0);
        c1 = MFMA(a1, w2f[kt], c1);
    }

    const int col = wave * 16 + r0;
    #pragma unroll
    for (int i = 0; i < 4; ++i) {
        out[(size_t)(q * 4 + i) * DIM + col]      = c0[i] + b2v;
        out[(size_t)(16 + q * 4 + i) * DIM + col] = c1[i] + b2v;
    }
}

// ---------------- CSR construction ----------------

__global__ __launch_bounds__(256)
void hist_kernel(const int* __restrict__ dst_idx, int* __restrict__ deg) {
    const int e = blockIdx.x * 256 + threadIdx.x;
    if (e < N_EDGES) atomicAdd(&deg[dst_idx[e]], 1);
}

__global__ __launch_bounds__(1024)
void scan_a(const int* __restrict__ deg, int* __restrict__ tmp, int* __restrict__ partials) {
    __shared__ int sm[1024];
    const int t = threadIdx.x;
    const int i = blockIdx.x * 1024 + t;
    const int v = (i < N_NODES) ? deg[i] : 0;
    sm[t] = v; __syncthreads();
    for (int d = 1; d < 1024; d <<= 1) {
        int u = (t >= d) ? sm[t - d] : 0; __syncthreads();
        sm[t] += u; __syncthreads();
    }
    if (i < N_NODES) tmp[i] = sm[t] - v;          // block-local exclusive
    if (t == 1023) partials[blockIdx.x] = sm[t];
}

__global__ __launch_bounds__(128)
void scan_b(const int* __restrict__ partials, int* __restrict__ poffs) {
    __shared__ int sm[128];
    const int t = threadIdx.x;
    const int v = (t < 98) ? partials[t] : 0;
    sm[t] = v; __syncthreads();
    for (int d = 1; d < 128; d <<= 1) {
        int u = (t >= d) ? sm[t - d] : 0; __syncthreads();
        sm[t] += u; __syncthreads();
    }
    poffs[t] = sm[t] - v;                          // exclusive
}

__global__ __launch_bounds__(1024)
void scan_c(const int* __restrict__ tmp, const int* __restrict__ poffs,
            int* __restrict__ rowptr, int* __restrict__ cursor) {
    const int t = threadIdx.x;
    const int i = blockIdx.x * 1024 + t;
    if (i < N_NODES) {
        const int v = tmp[i] + poffs[blockIdx.x];
        rowptr[i] = v; cursor[i] = v;
    }
    if (i == 0) rowptr[N_NODES] = N_EDGES;
}

__global__ __launch_bounds__(256)
void scatter_kernel(const int* __restrict__ dst_idx, int* __restrict__ cursor,
                    int* __restrict__ perm) {
    const int e = blockIdx.x * 256 + threadIdx.x;
    if (e < N_EDGES) {
        const int pos = atomicAdd(&cursor[dst_idx[e]], 1);
        perm[pos] = e;
    }
}

// ---------------- agg gather: one wave per node, bf16 output ----------------

__global__ __launch_bounds__(256)
void agg_kernel(const float* __restrict__ edge_attr, const int* __restrict__ rowptr,
                const int* __restrict__ perm, ushort_t* __restrict__ agg_bf) {
    const int gw   = (blockIdx.x * 256 + threadIdx.x) >> 6;   // node id
    const int lane = threadIdx.x & 63;
    if (gw >= N_NODES) return;
    const int k0 = rowptr[gw], k1 = rowptr[gw + 1];
    float a0 = 0.f, a1 = 0.f;
    int e0 = 0, e1 = 0;
    if (k0 < k1)     e0 = perm[k0];
    if (k0 + 1 < k1) e1 = perm[k0 + 1];
    for (int k = k0; k < k1; ++k) {
        const float2 v = *(const float2*)&edge_attr[(size_t)e0 * DIM + lane * 2];
        e0 = e1;
        if (k + 2 < k1) e1 = perm[k + 2];          // 2-deep perm prefetch
        a0 += v.x; a1 += v.y;
    }
    const unsigned int pk = (unsigned int)f2bf(a0) | ((unsigned int)f2bf(a1) << 16);
    *(unsigned int*)&agg_bf[(size_t)gw * DIM + lane * 2] = pk;
}

// ---------------- main MLP kernels (512 threads, 8 waves) ----------------

__global__ __launch_bounds__(512)
void edge_kernel(const float* __restrict__ x, const float* __restrict__ edge_attr,
                 const int* __restrict__ src_idx, const int* __restrict__ dst_idx,
                 const float* __restrict__ W1, const float* __restrict__ b1,
                 const float* __restrict__ W2, const float* __restrict__ b2,
                 float* __restrict__ e_out)
{
    __shared__ ushort_t s_in[32 * 256];   // 16 KB
    __shared__ ushort_t s_h[32 * 128];    // 8 KB
    const int tid = threadIdx.x, wave = tid >> 6, lane = tid & 63;

    short8 w1f[8], w2f[4];
    const float b1v = b1[wave * 16 + (lane & 15)];
    const float b2v = b2[wave * 16 + (lane & 15)];
    #pragma unroll
    for (int kt = 0; kt < 8; ++kt) w1f[kt] = load_bfrag(W1, wave, kt, lane);
    #pragma unroll
    for (int kt = 0; kt < 4; ++kt) w2f[kt] = load_bfrag(W2, wave, kt, lane);

    const int r = tid >> 4, gq = tid & 15, swr = r & 7;
    ushort_t* w_ea = &s_in[r * 256 + (gq ^ swr) * 8];
    ushort_t* w_x  = &s_in[r * 256 + ((16 + gq) ^ swr) * 8];

    const int ntiles = N_EDGES / 32;
    int t = blockIdx.x;
    float4 ea0, ea1, xs0, xs1, xd0, xd1;
    if (t < ntiles) {                                    // prologue loads (tile t)
        const int eb = t * 32;
        const int s = src_idx[eb + r], d = dst_idx[eb + r];
        const float* pe = edge_attr + (size_t)(eb + r) * DIM + gq * 8;
        ea0 = *(const float4*)pe; ea1 = *(const float4*)(pe + 4);
        const float* ps = x + (size_t)s * DIM + gq * 8;
        const float* pd = x + (size_t)d * DIM + gq * 8;
        xs0 = *(const float4*)ps; xs1 = *(const float4*)(ps + 4);
        xd0 = *(const float4*)pd; xd1 = *(const float4*)(pd + 4);
    }
    for (; t < ntiles; t += gridDim.x) {
        // pack current tile registers -> LDS (prev iter's s_in readers done pre-B2)
        *(short8*)w_ea = pack8(ea0, ea1);
        float4 u0, u1;
        u0.x = xs0.x + xd0.x; u0.y = xs0.y + xd0.y; u0.z = xs0.z + xd0.z; u0.w = xs0.w + xd0.w;
        u1.x = xs1.x + xd1.x; u1.y = xs1.y + xd1.y; u1.z = xs1.z + xd1.z; u1.w = xs1.w + xd1.w;
        *(short8*)w_x = pack8(u0, u1);

        const int tn = t + gridDim.x;
        const bool more = tn < ntiles;                   // block-uniform
        int sN = 0, dN = 0;
        if (more) { sN = src_idx[tn * 32 + r]; dN = dst_idx[tn * 32 + r]; }
        __syncthreads();                                 // B1: staging visible
        if (more) {                                      // prefetch tile t+G under MFMA
            const float* pe = edge_attr + (size_t)(tn * 32 + r) * DIM + gq * 8;
            ea0 = *(const float4*)pe; ea1 = *(const float4*)(pe + 4);
            const float* ps = x + (size_t)sN * DIM + gq * 8;
            const float* pd = x + (size_t)dN * DIM + gq * 8;
            xs0 = *(const float4*)ps; xs1 = *(const float4*)(ps + 4);
            xd0 = *(const float4*)pd; xd1 = *(const float4*)(pd + 4);
        }
        mlp_core(s_in, s_h, w1f, w2f, b1v, b2v,
                 e_out + (size_t)t * 32 * DIM, wave, lane);
    }
}

__global__ __launch_bounds__(512)
void node_kernel(const float* __restrict__ x, const ushort_t* __restrict__ agg_bf,
                 const float* __restrict__ W1, const float* __restrict__ b1,
                 const float* __restrict__ W2, const float* __restrict__ b2,
                 float* __restrict__ x_out)
{
    __shared__ ushort_t s_in[32 * 256];
    __shared__ ushort_t s_h[32 * 128];
    const int tid = threadIdx.x, wave = tid >> 6, lane = tid & 63;

    short8 w1f[8], w2f[4];
    const float b1v = b1[wave * 16 + (lane & 15)];
    const float b2v = b2[wave * 16 + (lane & 15)];
    #pragma unroll
    for (int kt = 0; kt < 8; ++kt) w1f[kt] = load_bfrag(W1, wave, kt, lane);
    #pragma unroll
    for (int kt = 0; kt < 4; ++kt) w2f[kt] = load_bfrag(W2, wave, kt, lane);

    const int r = tid >> 4, gq = tid & 15, swr = r & 7;
    ushort_t* w_xp = &s_in[r * 256 + (gq ^ swr) * 8];
    ushort_t* w_ag = &s_in[r * 256 + ((16 + gq) ^ swr) * 8];

    const int ntiles = N_NODES / 32;   // 3125
    for (int t = blockIdx.x; t < ntiles; t += gridDim.x) {
        const int nb = t * 32;
        const float* px = x + (size_t)(nb + r) * DIM + gq * 8;
        *(short8*)w_xp = pack8(*(const float4*)px, *(const float4*)(px + 4));
        *(short8*)w_ag = *(const short8*)&agg_bf[(size_t)(nb + r) * DIM + gq * 8];
        __syncthreads();                               // B1
        mlp_core(s_in, s_h, w1f, w2f, b1v, b2v,
                 x_out + (size_t)nb * DIM, wave, lane);
    }
}

extern "C" void kernel_launch(void* const* d_in, const int* in_sizes, int n_in,
                              void* d_out, int out_size, void* d_ws, size_t ws_size,
                              hipStream_t stream)
{
    const float* x         = (const float*)d_in[0];
    const float* edge_attr = (const float*)d_in[1];
    const int*   ei        = (const int*)d_in[2];   // [2, E]: src row then dst row
    const float* eW1 = (const float*)d_in[3];
    const float* eb1 = (const float*)d_in[4];
    const float* eW2 = (const float*)d_in[5];
    const float* eb2 = (const float*)d_in[6];
    const float* nW1 = (const float*)d_in[7];
    const float* nb1 = (const float*)d_in[8];
    const float* nW2 = (const float*)d_in[9];
    const float* nb2 = (const float*)d_in[10];

    float* out   = (float*)d_out;
    float* x_out = out;                             // [N, 128]
    float* e_out = out + (size_t)N_NODES * DIM;     // [E, 128]

    const int* src_idx = ei;
    const int* dst_idx = ei + N_EDGES;

    // workspace (ints): deg | tmp | rowptr | cursor | perm | partials | poffs, then bf16 agg
    int* wsi      = (int*)d_ws;
    int* deg      = wsi;
    int* tmp      = wsi + 100352;
    int* rowptr   = wsi + 200704;
    int* cursor   = wsi + 301056;
    int* perm     = wsi + 401408;
    int* partials = wsi + 1001472;
    int* poffs    = wsi + 1001600;
    ushort_t* agg_bf = (ushort_t*)(wsi + 1048576);  // 4 MiB offset, 25.6 MB

    hipMemsetAsync(deg, 0, (size_t)N_NODES * sizeof(int), stream);

    const int egrid = (N_EDGES + 255) / 256;
    hist_kernel   <<<dim3(egrid), dim3(256),  0, stream>>>(dst_idx, deg);
    scan_a        <<<dim3(98),    dim3(1024), 0, stream>>>(deg, tmp, partials);
    scan_b        <<<dim3(1),     dim3(128),  0, stream>>>(partials, poffs);
    scan_c        <<<dim3(98),    dim3(1024), 0, stream>>>(tmp, poffs, rowptr, cursor);
    scatter_kernel<<<dim3(egrid), dim3(256),  0, stream>>>(dst_idx, cursor, perm);

    agg_kernel<<<dim3(25000), dim3(256), 0, stream>>>(edge_attr, rowptr, perm, agg_bf);

    edge_kernel<<<dim3(2048), dim3(512), 0, stream>>>(
        x, edge_attr, src_idx, dst_idx, eW1, eb1, eW2, eb2, e_out);

    node_kernel<<<dim3(2048), dim3(512), 0, stream>>>(
        x, agg_bf, nW1, nb1, nW2, nb2, x_out);
}

// Round 5
// 410.415 us; speedup vs baseline: 5.4841x; 1.0017x over previous
//
#include <hip/hip_runtime.h>

#define N_NODES 100000
#define N_EDGES 600000
#define DIM 128

typedef __attribute__((ext_vector_type(8))) short short8;   // 8 bf16 (4 VGPRs)
typedef __attribute__((ext_vector_type(4))) float floatx4;  // MFMA C/D frag
typedef unsigned short ushort_t;

#define MFMA(a,b,c) __builtin_amdgcn_mfma_f32_16x16x32_bf16((a),(b),(c),0,0,0)

__device__ __forceinline__ unsigned short f2bf(float f) {
    unsigned int u = __float_as_uint(f);
    u += 0x7fffu + ((u >> 16) & 1u);   // round-to-nearest-even
    return (unsigned short)(u >> 16);
}

__device__ __forceinline__ short8 pack8(const float4& a, const float4& b) {
    short8 r;
    r[0] = (short)f2bf(a.x); r[1] = (short)f2bf(a.y);
    r[2] = (short)f2bf(a.z); r[3] = (short)f2bf(a.w);
    r[4] = (short)f2bf(b.x); r[5] = (short)f2bf(b.y);
    r[6] = (short)f2bf(b.z); r[7] = (short)f2bf(b.w);
    return r;
}

__device__ __forceinline__ float mish_f(float v) {
    if (v > 30.0f) return v;
    float t = __expf(v);
    float z = 1.0f + t;
    float z2 = z * z;
    return v * (z2 - 1.0f) / (z2 + 1.0f);
}

// B-fragment of W (row-major [K][128] fp32) for col-tile ct, k-tile kt.
__device__ __forceinline__ short8 load_bfrag(const float* __restrict__ W,
                                             int ct, int kt, int lane) {
    const float* p = W + (size_t)(kt * 32 + (lane >> 4) * 8) * DIM + ct * 16 + (lane & 15);
    short8 r;
    #pragma unroll
    for (int j = 0; j < 8; ++j) r[j] = (short)f2bf(p[(size_t)j * DIM]);
    return r;
}

// MLP compute on a staged 32-row tile. 8 waves; wave w owns cols [16w,16w+16).
// s_in/s_h: XOR-granule swizzle (granule=16B, phys = g ^ (row&7)).
__device__ __forceinline__ void mlp_core(
    const ushort_t* __restrict__ s_in, ushort_t* __restrict__ s_h,
    const short8 (&w1f)[8], const short8 (&w2f)[4],
    float b1v, float b2v, float* __restrict__ out, int wave, int lane)
{
    const int r0 = lane & 15, q = lane >> 4, sw = lane & 7;

    floatx4 acc0 = {0.f,0.f,0.f,0.f}, acc1 = acc0;
    #pragma unroll
    for (int kt = 0; kt < 8; ++kt) {
        const int g = kt * 4 + q;
        short8 a0 = *(const short8*)&s_in[r0 * 256 + (g ^ sw) * 8];
        short8 a1 = *(const short8*)&s_in[(16 + r0) * 256 + (g ^ sw) * 8];
        acc0 = MFMA(a0, w1f[kt], acc0);
        acc1 = MFMA(a1, w1f[kt], acc1);
    }

    const int colg = wave * 2 + (r0 >> 3);   // 8-col granule index of our column
    const int bq   = r0 & 7;
    #pragma unroll
    for (int i = 0; i < 4; ++i) {
        int row = q * 4 + i;
        s_h[row * 128 + (colg ^ (row & 7)) * 8 + bq] = f2bf(mish_f(acc0[i] + b1v));
        row += 16;
        s_h[row * 128 + (colg ^ (row & 7)) * 8 + bq] = f2bf(mish_f(acc1[i] + b1v));
    }
    __syncthreads();   // B2: s_h visible

    floatx4 c0 = {0.f,0.f,0.f,0.f}, c1 = c0;
    #pragma unroll
    for (int kt = 0; kt < 4; ++kt) {
        const int g = kt * 4 + q;
        short8 a0 = *(const short8*)&s_h[r0 * 128 + (g ^ sw) * 8];
        short8 a1 = *(const short8*)&s_h[(16 + r0) * 128 + (g ^ sw) * 8];
        c0 = MFMA(a0, w2f[kt], c0);
        c1 = MFMA(a1, w2f[kt], c1);
    }

    const int col = wave * 16 + r0;
    #pragma unroll
    for (int i = 0; i < 4; ++i) {
        out[(size_t)(q * 4 + i) * DIM + col]      = c0[i] + b2v;
        out[(size_t)(16 + q * 4 + i) * DIM + col] = c1[i] + b2v;
    }
}

// ---------------- CSR construction ----------------

__global__ __launch_bounds__(256)
void zero_kernel(int* __restrict__ p, int n) {     // replaces in-graph hipMemsetAsync
    const int i = blockIdx.x * 256 + threadIdx.x;  // (rocclr fill replays at ~205us!)
    if (i < n) p[i] = 0;
}

__global__ __launch_bounds__(256)
void hist_kernel(const int* __restrict__ dst_idx, int* __restrict__ deg) {
    const int e = blockIdx.x * 256 + threadIdx.x;
    if (e < N_EDGES) atomicAdd(&deg[dst_idx[e]], 1);
}

__global__ __launch_bounds__(1024)
void scan_a(const int* __restrict__ deg, int* __restrict__ tmp, int* __restrict__ partials) {
    __shared__ int sm[1024];
    const int t = threadIdx.x;
    const int i = blockIdx.x * 1024 + t;
    const int v = (i < N_NODES) ? deg[i] : 0;
    sm[t] = v; __syncthreads();
    for (int d = 1; d < 1024; d <<= 1) {
        int u = (t >= d) ? sm[t - d] : 0; __syncthreads();
        sm[t] += u; __syncthreads();
    }
    if (i < N_NODES) tmp[i] = sm[t] - v;          // block-local exclusive
    if (t == 1023) partials[blockIdx.x] = sm[t];
}

__global__ __launch_bounds__(128)
void scan_b(const int* __restrict__ partials, int* __restrict__ poffs) {
    __shared__ int sm[128];
    const int t = threadIdx.x;
    const int v = (t < 98) ? partials[t] : 0;
    sm[t] = v; __syncthreads();
    for (int d = 1; d < 128; d <<= 1) {
        int u = (t >= d) ? sm[t - d] : 0; __syncthreads();
        sm[t] += u; __syncthreads();
    }
    poffs[t] = sm[t] - v;                          // exclusive
}

__global__ __launch_bounds__(1024)
void scan_c(const int* __restrict__ tmp, const int* __restrict__ poffs,
            int* __restrict__ rowptr, int* __restrict__ cursor) {
    const int t = threadIdx.x;
    const int i = blockIdx.x * 1024 + t;
    if (i < N_NODES) {
        const int v = tmp[i] + poffs[blockIdx.x];
        rowptr[i] = v; cursor[i] = v;
    }
    if (i == 0) rowptr[N_NODES] = N_EDGES;
}

__global__ __launch_bounds__(256)
void scatter_kernel(const int* __restrict__ dst_idx, int* __restrict__ cursor,
                    int* __restrict__ perm) {
    const int e = blockIdx.x * 256 + threadIdx.x;
    if (e < N_EDGES) {
        const int pos = atomicAdd(&cursor[dst_idx[e]], 1);
        perm[pos] = e;
    }
}

// ---------------- agg gather: one wave per node, bf16 output ----------------

__global__ __launch_bounds__(256)
void agg_kernel(const float* __restrict__ edge_attr, const int* __restrict__ rowptr,
                const int* __restrict__ perm, ushort_t* __restrict__ agg_bf) {
    const int gw   = (blockIdx.x * 256 + threadIdx.x) >> 6;   // node id
    const int lane = threadIdx.x & 63;
    if (gw >= N_NODES) return;
    const int k0 = rowptr[gw], k1 = rowptr[gw + 1];
    float a0 = 0.f, a1 = 0.f;
    int e0 = 0, e1 = 0;
    if (k0 < k1)     e0 = perm[k0];
    if (k0 + 1 < k1) e1 = perm[k0 + 1];
    for (int k = k0; k < k1; ++k) {
        const float2 v = *(const float2*)&edge_attr[(size_t)e0 * DIM + lane * 2];
        e0 = e1;
        if (k + 2 < k1) e1 = perm[k + 2];          // 2-deep perm prefetch
        a0 += v.x; a1 += v.y;
    }
    const unsigned int pk = (unsigned int)f2bf(a0) | ((unsigned int)f2bf(a1) << 16);
    *(unsigned int*)&agg_bf[(size_t)gw * DIM + lane * 2] = pk;
}

// ---------------- main MLP kernels (512 threads, 8 waves) ----------------

__global__ __launch_bounds__(512)
void edge_kernel(const float* __restrict__ x, const float* __restrict__ edge_attr,
                 const int* __restrict__ src_idx, const int* __restrict__ dst_idx,
                 const float* __restrict__ W1, const float* __restrict__ b1,
                 const float* __restrict__ W2, const float* __restrict__ b2,
                 float* __restrict__ e_out)
{
    __shared__ ushort_t s_in[32 * 256];   // 16 KB
    __shared__ ushort_t s_h[32 * 128];    // 8 KB
    const int tid = threadIdx.x, wave = tid >> 6, lane = tid & 63;

    short8 w1f[8], w2f[4];
    const float b1v = b1[wave * 16 + (lane & 15)];
    const float b2v = b2[wave * 16 + (lane & 15)];
    #pragma unroll
    for (int kt = 0; kt < 8; ++kt) w1f[kt] = load_bfrag(W1, wave, kt, lane);
    #pragma unroll
    for (int kt = 0; kt < 4; ++kt) w2f[kt] = load_bfrag(W2, wave, kt, lane);

    const int r = tid >> 4, gq = tid & 15, swr = r & 7;
    ushort_t* w_ea = &s_in[r * 256 + (gq ^ swr) * 8];
    ushort_t* w_x  = &s_in[r * 256 + ((16 + gq) ^ swr) * 8];

    const int ntiles = N_EDGES / 32;
    int t = blockIdx.x;
    float4 ea0, ea1, xs0, xs1, xd0, xd1;
    if (t < ntiles) {                                    // prologue loads (tile t)
        const int eb = t * 32;
        const int s = src_idx[eb + r], d = dst_idx[eb + r];
        const float* pe = edge_attr + (size_t)(eb + r) * DIM + gq * 8;
        ea0 = *(const float4*)pe; ea1 = *(const float4*)(pe + 4);
        const float* ps = x + (size_t)s * DIM + gq * 8;
        const float* pd = x + (size_t)d * DIM + gq * 8;
        xs0 = *(const float4*)ps; xs1 = *(const float4*)(ps + 4);
        xd0 = *(const float4*)pd; xd1 = *(const float4*)(pd + 4);
    }
    for (; t < ntiles; t += gridDim.x) {
        // pack current tile registers -> LDS (prev iter's s_in readers done pre-B2)
        *(short8*)w_ea = pack8(ea0, ea1);
        float4 u0, u1;
        u0.x = xs0.x + xd0.x; u0.y = xs0.y + xd0.y; u0.z = xs0.z + xd0.z; u0.w = xs0.w + xd0.w;
        u1.x = xs1.x + xd1.x; u1.y = xs1.y + xd1.y; u1.z = xs1.z + xd1.z; u1.w = xs1.w + xd1.w;
        *(short8*)w_x = pack8(u0, u1);

        const int tn = t + gridDim.x;
        const bool more = tn < ntiles;                   // block-uniform
        int sN = 0, dN = 0;
        if (more) { sN = src_idx[tn * 32 + r]; dN = dst_idx[tn * 32 + r]; }
        __syncthreads();                                 // B1: staging visible
        if (more) {                                      // prefetch tile t+G under MFMA
            const float* pe = edge_attr + (size_t)(tn * 32 + r) * DIM + gq * 8;
            ea0 = *(const float4*)pe; ea1 = *(const float4*)(pe + 4);
            const float* ps = x + (size_t)sN * DIM + gq * 8;
            const float* pd = x + (size_t)dN * DIM + gq * 8;
            xs0 = *(const float4*)ps; xs1 = *(const float4*)(ps + 4);
            xd0 = *(const float4*)pd; xd1 = *(const float4*)(pd + 4);
        }
        mlp_core(s_in, s_h, w1f, w2f, b1v, b2v,
                 e_out + (size_t)t * 32 * DIM, wave, lane);
    }
}

__global__ __launch_bounds__(512)
void node_kernel(const float* __restrict__ x, const ushort_t* __restrict__ agg_bf,
                 const float* __restrict__ W1, const float* __restrict__ b1,
                 const float* __restrict__ W2, const float* __restrict__ b2,
                 float* __restrict__ x_out)
{
    __shared__ ushort_t s_in[32 * 256];
    __shared__ ushort_t s_h[32 * 128];
    const int tid = threadIdx.x, wave = tid >> 6, lane = tid & 63;

    short8 w1f[8], w2f[4];
    const float b1v = b1[wave * 16 + (lane & 15)];
    const float b2v = b2[wave * 16 + (lane & 15)];
    #pragma unroll
    for (int kt = 0; kt < 8; ++kt) w1f[kt] = load_bfrag(W1, wave, kt, lane);
    #pragma unroll
    for (int kt = 0; kt < 4; ++kt) w2f[kt] = load_bfrag(W2, wave, kt, lane);

    const int r = tid >> 4, gq = tid & 15, swr = r & 7;
    ushort_t* w_xp = &s_in[r * 256 + (gq ^ swr) * 8];
    ushort_t* w_ag = &s_in[r * 256 + ((16 + gq) ^ swr) * 8];

    const int ntiles = N_NODES / 32;   // 3125
    for (int t = blockIdx.x; t < ntiles; t += gridDim.x) {
        const int nb = t * 32;
        const float* px = x + (size_t)(nb + r) * DIM + gq * 8;
        *(short8*)w_xp = pack8(*(const float4*)px, *(const float4*)(px + 4));
        *(short8*)w_ag = *(const short8*)&agg_bf[(size_t)(nb + r) * DIM + gq * 8];
        __syncthreads();                               // B1
        mlp_core(s_in, s_h, w1f, w2f, b1v, b2v,
                 x_out + (size_t)nb * DIM, wave, lane);
    }
}

extern "C" void kernel_launch(void* const* d_in, const int* in_sizes, int n_in,
                              void* d_out, int out_size, void* d_ws, size_t ws_size,
                              hipStream_t stream)
{
    const float* x         = (const float*)d_in[0];
    const float* edge_attr = (const float*)d_in[1];
    const int*   ei        = (const int*)d_in[2];   // [2, E]: src row then dst row
    const float* eW1 = (const float*)d_in[3];
    const float* eb1 = (const float*)d_in[4];
    const float* eW2 = (const float*)d_in[5];
    const float* eb2 = (const float*)d_in[6];
    const float* nW1 = (const float*)d_in[7];
    const float* nb1 = (const float*)d_in[8];
    const float* nW2 = (const float*)d_in[9];
    const float* nb2 = (const float*)d_in[10];

    float* out   = (float*)d_out;
    float* x_out = out;                             // [N, 128]
    float* e_out = out + (size_t)N_NODES * DIM;     // [E, 128]

    const int* src_idx = ei;
    const int* dst_idx = ei + N_EDGES;

    // workspace (ints): deg | tmp | rowptr | cursor | perm | partials | poffs, then bf16 agg
    int* wsi      = (int*)d_ws;
    int* deg      = wsi;
    int* tmp      = wsi + 100352;
    int* rowptr   = wsi + 200704;
    int* cursor   = wsi + 301056;
    int* perm     = wsi + 401408;
    int* partials = wsi + 1001472;
    int* poffs    = wsi + 1001600;
    ushort_t* agg_bf = (ushort_t*)(wsi + 1048576);  // 4 MiB offset, 25.6 MB

    const int egrid = (N_EDGES + 255) / 256;
    zero_kernel   <<<dim3(392),   dim3(256),  0, stream>>>(deg, 100352);
    hist_kernel   <<<dim3(egrid), dim3(256),  0, stream>>>(dst_idx, deg);
    scan_a        <<<dim3(98),    dim3(1024), 0, stream>>>(deg, tmp, partials);
    scan_b        <<<dim3(1),     dim3(128),  0, stream>>>(partials, poffs);
    scan_c        <<<dim3(98),    dim3(1024), 0, stream>>>(tmp, poffs, rowptr, cursor);
    scatter_kernel<<<dim3(egrid), dim3(256),  0, stream>>>(dst_idx, cursor, perm);

    agg_kernel<<<dim3(25000), dim3(256), 0, stream>>>(edge_attr, rowptr, perm, agg_bf);

    edge_kernel<<<dim3(2048), dim3(512), 0, stream>>>(
        x, edge_attr, src_idx, dst_idx, eW1, eb1, eW2, eb2, e_out);

    node_kernel<<<dim3(2048), dim3(512), 0, stream>>>(
        x, agg_bf, nW1, nb1, nW2, nb2, x_out);
}